// Round 3
// baseline (799.008 us; speedup 1.0000x reference)
//
#include <hip/hip_runtime.h>

// HBMA fused: full-search block matching (16x16 blocks, +/-4 search) + predicted
// frame gather. N=8, C=3, H=W=1024.
//
// R3 = R2 with the compile error fixed (stray placeholder constexpr removed).
// Design: one 64-lane wave per 64-wide x 16-tall strip (4 blocks). Lane =
// column. The 9 dy displacements are split into 3 fully-unrolled passes of 3
// so only acc[3][9]=27 accumulators are live (R1 had acc[81] -> VGPR cap 256
// -> spills). Ref strip is staged one channel at a time (24x72 floats =
// 6.75 KB LDS, vs 20.5 KB) -> ~16 waves/CU occupancy instead of 7. Ref strip
// re-staged per (pass, channel) - L3-hot, cheap. Final gather reads ref
// directly from global (coalesced per 16-lane block group, L2-hot).

namespace {
constexpr int BLKi  = 16;
constexpr int NSDi  = 4;
constexpr int ND    = 2 * NSDi + 1;        // 9 displacements per axis
constexpr int Nn    = 8;
constexpr int Cc    = 3;
constexpr int Hh    = 1024;
constexpr int Ww    = 1024;
constexpr int BHn   = Hh / BLKi;           // 64
constexpr int BWn   = Ww / BLKi;           // 64
constexpr int STRIPW = 64;                 // columns handled per wave
constexpr int NSTRIPS = Ww / STRIPW;       // 16
constexpr int REFW  = STRIPW + 2 * NSDi;   // 72
constexpr int REFH  = BLKi + 2 * NSDi;     // 24
constexpr int REF_ELEMS = REFH * REFW;     // 1728 floats (one channel)
constexpr int MV_SIZE = Nn * 2 * BHn * BWn; // 65536
constexpr int PASSES = 3;
constexpr int JP     = 3;                  // dy values per pass
}

__global__ void zero_mv_kernel(float* __restrict__ out) {
    int i = blockIdx.x * 256 + threadIdx.x;
    if (i < MV_SIZE) out[i] = 0.0f;
}

__global__ __launch_bounds__(64) void hbma_kernel(
        const float* __restrict__ ref,
        const float* __restrict__ tgt,
        float* __restrict__ pred) {
    __shared__ float lds[REF_ELEMS];          // one channel's zero-padded strip

    const int lane = (int)threadIdx.x;        // 0..63 = column within strip
    const int b    = (int)blockIdx.x;         // 0..8191
    const int n    = b >> 10;                 // 1024 strips per batch image
    const int rem  = b & 1023;
    const int Y0   = (rem >> 4) * BLKi;       // block-row * 16
    const int X0   = (rem & 15) * STRIPW;     // strip * 64
    const float* refn = ref + (size_t)n * Cc * Hh * Ww;
    const float* tgtn = tgt + (size_t)n * Cc * Hh * Ww;
    float*       predn = pred + (size_t)n * Cc * Hh * Ww;

    float best = 3.4e38f;
    int   bidx = 0;                           // reference disp index (dy+4)*9+(dx+4)

    #pragma unroll
    for (int p = 0; p < PASSES; ++p) {        // dy groups: j = dy+4 in [3p, 3p+3)
        const int j0 = p * JP;

        float acc[JP][ND];
        #pragma unroll
        for (int jj = 0; jj < JP; ++jj)
            #pragma unroll
            for (int d = 0; d < ND; ++d) acc[jj][d] = 0.0f;

        for (int c = 0; c < Cc; ++c) {
            __syncthreads();
            // ---- stage zero-padded ref strip for channel c: [r(24)][col(72)] ----
            #pragma unroll
            for (int k = 0; k < REF_ELEMS / 64; ++k) {   // 27 iterations
                int idx = k * 64 + lane;
                int r   = idx / REFW;
                int col = idx - r * REFW;
                int gy  = Y0 - NSDi + r;
                int gx  = X0 - NSDi + col;
                float v = 0.0f;
                if ((unsigned)gy < (unsigned)Hh && (unsigned)gx < (unsigned)Ww)
                    v = refn[((size_t)c * Hh + gy) * Ww + gx];
                lds[idx] = v;
            }
            __syncthreads();

            // target rows for this channel, this lane's column
            float T[BLKi];
            #pragma unroll
            for (int y = 0; y < BLKi; ++y)
                T[y] = tgtn[((size_t)c * Hh + (Y0 + y)) * Ww + X0 + lane];

            // rows needed this pass: r in [j0, j0+17]  (y = r - j, j in [j0,j0+2])
            #pragma unroll
            for (int rr = 0; rr < BLKi + JP - 1; ++rr) { // 18 rows
                const int r = j0 + rr;
                float rv[ND];
                #pragma unroll
                for (int d = 0; d < ND; ++d)
                    rv[d] = lds[r * REFW + lane + d];
                #pragma unroll
                for (int jj = 0; jj < JP; ++jj) {
                    const int y = rr - jj;                // = r - (j0+jj), compile-time
                    if (y >= 0 && y < BLKi) {
                        float tv = T[y];
                        #pragma unroll
                        for (int d = 0; d < ND; ++d)
                            acc[jj][d] += fabsf(rv[d] - tv);
                    }
                }
            }
        }

        // ---- reduce across the 16 lanes of each block group ----
        #pragma unroll
        for (int m = 1; m <= 8; m <<= 1)
            #pragma unroll
            for (int jj = 0; jj < JP; ++jj)
                #pragma unroll
                for (int d = 0; d < ND; ++d)
                    acc[jj][d] += __shfl_xor(acc[jj][d], m, 64);

        // ---- fold into running argmin (ascending reference index, strict <) ----
        #pragma unroll
        for (int jj = 0; jj < JP; ++jj)
            #pragma unroll
            for (int d = 0; d < ND; ++d) {
                float cst = acc[jj][d];
                if (cst < best) { best = cst; bidx = (j0 + jj) * ND + d; }
            }
    }

    const int bdy = bidx / ND - NSDi;
    const int bdx = bidx % ND - NSDi;

    // ---- gather predicted frame directly from global ref (zero padded) ----
    const int gx = X0 + lane + bdx;
    const bool xin = (unsigned)gx < (unsigned)Ww;
    for (int c = 0; c < Cc; ++c) {
        #pragma unroll
        for (int y = 0; y < BLKi; ++y) {
            int gy = Y0 + y + bdy;
            float v = 0.0f;
            if (xin && (unsigned)gy < (unsigned)Hh)
                v = refn[((size_t)c * Hh + gy) * Ww + gx];
            predn[((size_t)c * Hh + (Y0 + y)) * Ww + X0 + lane] = v;
        }
    }
}

extern "C" void kernel_launch(void* const* d_in, const int* in_sizes, int n_in,
                              void* d_out, int out_size, void* d_ws, size_t ws_size,
                              hipStream_t stream) {
    const float* ref = (const float*)d_in[0];
    const float* tgt = (const float*)d_in[1];
    float* out = (float*)d_out;

    zero_mv_kernel<<<dim3((MV_SIZE + 255) / 256), dim3(256), 0, stream>>>(out);

    const int nblocks = Nn * BHn * NSTRIPS;  // 8 * 64 * 16 = 8192
    hbma_kernel<<<dim3(nblocks), dim3(64), 0, stream>>>(ref, tgt, out + MV_SIZE);
}

// Round 4
// 358.696 us; speedup vs baseline: 2.2275x; 2.2275x over previous
//
#include <hip/hip_runtime.h>

// HBMA fused: full-search block matching (16x16 blocks, +/-4 search) + predicted
// frame gather. N=8, C=3, H=W=1024.
//
// R4 design: one 192-thread workgroup (3 waves) per 64-wide x 16-tall strip
// (4 blocks). Lane = column within strip. The 9 dx displacements are split
// across the 3 waves (wave w: dx-idx {3w,3w+1,3w+2}), each wave keeping
// acc[9 dy][3 dx] = 27 live accumulators (no spills). Ref strip (3ch x 24 x 72,
// zero-padded, 20.25 KB) is staged ONCE per workgroup cooperatively, unlike
// R3's 9x re-staging (which was latency-bound at 11% occupancy). Per-wave
// sums are 16-lane shfl-reduced, written to an LDS cost array [4][81], then a
// parallel argmin with ascending-index tie-break (matches jax scan's strict <)
// picks the displacement; the predicted frame is gathered straight from the
// LDS ref strip (already zero-padded -> no bounds checks, no global re-read).

namespace {
constexpr int BLKi  = 16;
constexpr int NSDi  = 4;
constexpr int ND    = 2 * NSDi + 1;          // 9 displacements per axis
constexpr int NDISP = ND * ND;               // 81
constexpr int Nn    = 8;
constexpr int Cc    = 3;
constexpr int Hh    = 1024;
constexpr int Ww    = 1024;
constexpr int BHn   = Hh / BLKi;             // 64
constexpr int BWn   = Ww / BLKi;             // 64
constexpr int STRIPW = 64;                   // columns handled per workgroup
constexpr int NSTRIPS = Ww / STRIPW;         // 16
constexpr int REFW  = STRIPW + 2 * NSDi;     // 72
constexpr int REFH  = BLKi + 2 * NSDi;       // 24
constexpr int REF_ELEMS = Cc * REFH * REFW;  // 5184 floats
constexpr int MV_SIZE = Nn * 2 * BHn * BWn;  // 65536
constexpr int WGSIZE = 192;                  // 3 waves
constexpr int DXW    = 3;                    // dx values per wave
constexpr int BLKS_PER_WG = STRIPW / BLKi;   // 4
}

__global__ void zero_mv_kernel(float* __restrict__ out) {
    int i = blockIdx.x * 256 + threadIdx.x;
    if (i < MV_SIZE) out[i] = 0.0f;
}

__global__ __launch_bounds__(WGSIZE) void hbma_kernel(
        const float* __restrict__ ref,
        const float* __restrict__ tgt,
        float* __restrict__ pred) {
    __shared__ float ldsR[REF_ELEMS];              // zero-padded ref strip
    __shared__ float costL[BLKS_PER_WG][NDISP];    // per-block costs
    __shared__ int   bestL[BLKS_PER_WG];           // per-block best disp idx

    const int tid  = (int)threadIdx.x;
    const int wid  = tid >> 6;                     // 0..2
    const int lane = tid & 63;                     // column within strip
    const int b    = (int)blockIdx.x;              // 0..8191
    const int n    = b >> 10;                      // 1024 strips per image
    const int rem  = b & 1023;
    const int Y0   = (rem >> 4) * BLKi;            // block-row * 16
    const int X0   = (rem & 15) * STRIPW;          // strip * 64
    const float* refn  = ref  + (size_t)n * Cc * Hh * Ww;
    const float* tgtn  = tgt  + (size_t)n * Cc * Hh * Ww;
    float*       predn = pred + (size_t)n * Cc * Hh * Ww;

    // ---- stage zero-padded ref strip once: [c][r(24)][col(72)] ----
    #pragma unroll
    for (int t = 0; t < REF_ELEMS / WGSIZE; ++t) { // 27 iterations
        int idx = t * WGSIZE + tid;
        int c   = idx / (REFH * REFW);
        int r2  = idx - c * (REFH * REFW);
        int r   = r2 / REFW;
        int col = r2 - r * REFW;
        int gy  = Y0 - NSDi + r;
        int gx  = X0 - NSDi + col;
        float v = 0.0f;
        if ((unsigned)gy < (unsigned)Hh && (unsigned)gx < (unsigned)Ww)
            v = refn[((size_t)c * Hh + gy) * Ww + gx];
        ldsR[idx] = v;
    }
    __syncthreads();

    // ---- SAD: wave `wid` covers dx indices d0..d0+2, all 9 dy ----
    const int d0 = wid * DXW;                      // 0, 3, 6
    float acc[ND][DXW];
    #pragma unroll
    for (int jj = 0; jj < ND; ++jj)
        #pragma unroll
        for (int dd = 0; dd < DXW; ++dd) acc[jj][dd] = 0.0f;

    #pragma unroll 1
    for (int c = 0; c < Cc; ++c) {
        float T[BLKi];
        #pragma unroll
        for (int y = 0; y < BLKi; ++y)
            T[y] = tgtn[((size_t)c * Hh + (Y0 + y)) * Ww + X0 + lane];

        #pragma unroll
        for (int r = 0; r < REFH; ++r) {
            float rv[DXW];
            #pragma unroll
            for (int dd = 0; dd < DXW; ++dd)
                rv[dd] = ldsR[(c * REFH + r) * REFW + lane + d0 + dd];
            #pragma unroll
            for (int jj = 0; jj < ND; ++jj) {
                const int y = r - jj;              // compile-time after unroll
                if (y >= 0 && y < BLKi) {
                    float tv = T[y];
                    #pragma unroll
                    for (int dd = 0; dd < DXW; ++dd)
                        acc[jj][dd] += fabsf(rv[dd] - tv);
                }
            }
        }
    }

    // ---- reduce across the 16 lanes of each block group ----
    #pragma unroll
    for (int m = 1; m <= 8; m <<= 1)
        #pragma unroll
        for (int jj = 0; jj < ND; ++jj)
            #pragma unroll
            for (int dd = 0; dd < DXW; ++dd)
                acc[jj][dd] += __shfl_xor(acc[jj][dd], m, 64);

    // ---- publish costs: lane (sub==jj) of each 16-group writes its 3 dx ----
    const int bi  = lane >> 4;
    const int sub = lane & 15;
    #pragma unroll
    for (int jj = 0; jj < ND; ++jj) {
        if (sub == jj) {
            #pragma unroll
            for (int dd = 0; dd < DXW; ++dd)
                costL[bi][jj * ND + d0 + dd] = acc[jj][dd];
        }
    }
    __syncthreads();

    // ---- argmin (wave 0): ascending index, strict <, matching jax scan ----
    if (wid == 0) {
        float bc = 3.4e38f;
        int   bj = NDISP;
        #pragma unroll
        for (int k = 0; k < 6; ++k) {              // sub, sub+16, ... (<81)
            int j = sub + (k << 4);
            if (j < NDISP) {
                float cst = costL[bi][j];
                if (cst < bc) { bc = cst; bj = j; }
            }
        }
        #pragma unroll
        for (int m = 1; m <= 8; m <<= 1) {
            float oc = __shfl_xor(bc, m, 64);
            int   oi = __shfl_xor(bj, m, 64);
            if (oc < bc || (oc == bc && oi < bj)) { bc = oc; bj = oi; }
        }
        if (sub == 0) bestL[bi] = bj;
    }
    __syncthreads();

    // ---- gather predicted frame from the LDS strip (already zero-padded) ----
    const int x  = tid & 63;                       // column in strip
    const int gb = x >> 4;                         // block
    const int yy = tid >> 6;                       // 0..2 row phase
    const int bb = bestL[gb];
    const int by = bb / ND;                        // dy + 4
    const int bx = bb % ND;                        // dx + 4
    #pragma unroll 1
    for (int c = 0; c < Cc; ++c) {
        for (int y = yy; y < BLKi; y += 3) {
            float v = ldsR[(c * REFH + (y + by)) * REFW + (x + bx)];
            predn[((size_t)c * Hh + (Y0 + y)) * Ww + X0 + x] = v;
        }
    }
}

extern "C" void kernel_launch(void* const* d_in, const int* in_sizes, int n_in,
                              void* d_out, int out_size, void* d_ws, size_t ws_size,
                              hipStream_t stream) {
    const float* ref = (const float*)d_in[0];
    const float* tgt = (const float*)d_in[1];
    float* out = (float*)d_out;

    zero_mv_kernel<<<dim3((MV_SIZE + 255) / 256), dim3(256), 0, stream>>>(out);

    const int nblocks = Nn * BHn * NSTRIPS;  // 8 * 64 * 16 = 8192
    hbma_kernel<<<dim3(nblocks), dim3(WGSIZE), 0, stream>>>(ref, tgt, out + MV_SIZE);
}